// Round 15
// baseline (710.662 us; speedup 1.0000x reference)
//
#include <hip/hip_runtime.h>
#include <stdint.h>

#define NTOK 128
#define DHID 256
#define NHEAD 4
#define DHEAD 64

typedef short bf16x8 __attribute__((ext_vector_type(8)));
typedef float f32x4 __attribute__((ext_vector_type(4)));

#define MFMA(a,b,c) __builtin_amdgcn_mfma_f32_16x16x32_bf16((a),(b),(c),0,0,0)

__device__ __forceinline__ float bf2f(uint16_t u){
  union { uint32_t i; float f; } v; v.i = ((uint32_t)u) << 16; return v.f;
}
__device__ __forceinline__ uint16_t f2bf(float f){
  union { uint32_t i; float f; } v; v.f = f;
  uint32_t i = v.i + 0x7FFFu + ((v.i >> 16) & 1u);
  return (uint16_t)(i >> 16);
}

// ---------------- dtype probe ----------------
__global__ void k_detect(const uint32_t* __restrict__ raw, uint32_t* __restrict__ flag){
  int lane = threadIdx.x;
  int hits = 0;
  #pragma unroll
  for (int i = 0; i < 16; i++){
    uint32_t w = raw[lane*16 + i];
    uint32_t e = (w >> 7) & 0xFFu;
    hits += (e >= 0x70u && e <= 0x8Fu) ? 1 : 0;
  }
  #pragma unroll
  for (int m = 1; m < 64; m <<= 1) hits += __shfl_xor(hits, m);
  if (lane == 0) *flag = (hits > 512) ? 1u : 0u;   // 1 = bf16, 0 = fp32
}

// ---------------- merged weight conversion (fp32 path only) ----------------
__global__ __launch_bounds__(256) void k_convw(const uint32_t* __restrict__ flag,
    const void* Wq, const void* Wk, const void* Wv, const void* Wo,
    const void* Wih, const void* Whh,
    const void* bq, const void* bk, const void* bv, const void* bih, const void* bhh,
    uint16_t* __restrict__ dst)
{
  if (*flag) return;
  int blk = blockIdx.x, tid = threadIdx.x;
  if (blk < 224){
    const float* src; size_t doff; int so;
    if      (blk <  32){ src = (const float*)Wq;  doff = 0;      so = blk*2048; }
    else if (blk <  64){ src = (const float*)Wk;  doff = 65536;  so = (blk-32)*2048; }
    else if (blk <  96){ src = (const float*)Wv;  doff = 131072; so = (blk-64)*2048; }
    else if (blk < 104){ src = (const float*)Wo;  doff = 196608; so = (blk-96)*2048; }
    else if (blk < 128){ src = (const float*)Wih; doff = 212992; so = (blk-104)*2048; }
    else               { src = (const float*)Whh; doff = 262144; so = (blk-128)*2048; }
    int i = so + tid*8;
    float4 a = *(const float4*)(src + i);
    float4 b = *(const float4*)(src + i + 4);
    uint16_t o[8] = {f2bf(a.x),f2bf(a.y),f2bf(a.z),f2bf(a.w),
                     f2bf(b.x),f2bf(b.y),f2bf(b.z),f2bf(b.w)};
    *(bf16x8*)(dst + doff + i) = *(const bf16x8*)o;
  } else {
    for (int i = tid; i < 2304; i += 256){
      const float* s; int lo;
      if      (i <  256){ s = (const float*)bq;  lo = i; }
      else if (i <  512){ s = (const float*)bk;  lo = i - 256; }
      else if (i <  768){ s = (const float*)bv;  lo = i - 512; }
      else if (i < 1536){ s = (const float*)bih; lo = i - 768; }
      else              { s = (const float*)bhh; lo = i - 1536; }
      dst[458752 + i] = f2bf(s[lo]);
    }
  }
}

// ---------------- normalize latent to bf16 (both paths; bf16 = copy) ----------------
__global__ void k_conv(const void* __restrict__ src, unsigned long long off,
                       uint16_t* __restrict__ dst, const uint32_t* __restrict__ flag, int n){
  const int isbf = (int)*flag;
  int i0 = (blockIdx.x * blockDim.x + threadIdx.x) * 8;
  int stride = gridDim.x * blockDim.x * 8;
  if (isbf){
    const uint16_t* s = (const uint16_t*)src + off;
    for (int i = i0; i < n; i += stride)
      *(bf16x8*)(dst + i) = *(const bf16x8*)(s + i);
  } else {
    const float* s = (const float*)src + off;
    for (int i = i0; i < n; i += stride){
      float4 a = *(const float4*)(s + i);
      float4 b = *(const float4*)(s + i + 4);
      uint16_t o[8] = {f2bf(a.x),f2bf(a.y),f2bf(a.z),f2bf(a.w),
                       f2bf(b.x),f2bf(b.y),f2bf(b.z),f2bf(b.w)};
      *(bf16x8*)(dst + i) = *(const bf16x8*)o;
    }
  }
}

// ---------------- store result (fp32 path only; bf16 path: gru wrote d_out) ----------------
__global__ void k_store(const uint16_t* __restrict__ L, void* __restrict__ dst,
                        unsigned long long off, const uint32_t* __restrict__ flag, int n){
  if (*flag) return;
  int i0 = (blockIdx.x * blockDim.x + threadIdx.x) * 8;
  int stride = gridDim.x * blockDim.x * 8;
  float* d = (float*)dst + off;
  for (int i = i0; i < n; i += stride){
    bf16x8 v = *(const bf16x8*)(L + i);
    #pragma unroll
    for (int e = 0; e < 8; e++) d[i + e] = bf2f((uint16_t)v[e]);
  }
}

// ---------------- K0: pack mask rows ----------------
__global__ __launch_bounds__(256) void k_maskpack(const int* __restrict__ mask,
                                                  unsigned long long* __restrict__ packed,
                                                  unsigned char* __restrict__ upd, int nrows){
  int row = blockIdx.x * 4 + (threadIdx.x >> 6);
  if (row >= nrows) return;
  int lane = threadIdx.x & 63;
  const int* mrow = mask + (size_t)row * NTOK;
  unsigned long long b0 = __ballot(mrow[lane] != 0);
  unsigned long long b1 = __ballot(mrow[lane + 64] != 0);
  if (lane == 0){
    packed[row*2 + 0] = b0;
    packed[row*2 + 1] = b1;
    upd[row] = (unsigned char)((__popcll(b0) + __popcll(b1)) > 1 ? 1 : 0);
  }
}

// ---------------- K1 (R6 exact): QKV — stage X once, loop 12 weight tiles ----------------
__global__ __launch_bounds__(256) void k_qkv(
    const uint16_t* __restrict__ X,
    const uint16_t* __restrict__ Wq, const uint16_t* __restrict__ bq,
    const uint16_t* __restrict__ Wk, const uint16_t* __restrict__ bk,
    const uint16_t* __restrict__ Wv, const uint16_t* __restrict__ bv,
    uint16_t* __restrict__ Oq, uint16_t* __restrict__ Ok, uint16_t* __restrict__ Ov)
{
  extern __shared__ uint16_t sm[];
  uint16_t* Xs = sm;            // [64][256] swizzled
  uint16_t* Ws = sm + 64*256;   // [64][256] swizzled (per weight tile)
  const int r0 = blockIdx.x * 64;
  const int tid = threadIdx.x;
  const int lane = tid & 63, lr = lane & 15, lg = lane >> 4;
  const int wav = tid >> 6;
  const int wr = (wav >> 1) * 32, wc = (wav & 1) * 32;

  #pragma unroll
  for (int i = 0; i < 8; i++){
    int c = tid + i*256, row = c >> 5, g = c & 31;
    *(bf16x8*)(Xs + row*256 + (g ^ (row & 7))*8) =
        *(const bf16x8*)(X + (size_t)(r0+row)*DHID + g*8);
  }

  bf16x8 wreg[8];
  auto wptr = [&](int t)->const uint16_t*{
    int w = t >> 2;
    return (w == 0) ? Wq : ((w == 1) ? Wk : Wv);
  };
  auto preload = [&](int t){
    const uint16_t* W = wptr(t);
    int c0t = (t & 3) * 64;
    #pragma unroll
    for (int i = 0; i < 8; i++){
      int idx = tid + i*256, r = idx >> 5, g = idx & 31;
      wreg[i] = *(const bf16x8*)(W + (size_t)(c0t + r)*DHID + g*8);
    }
  };
  preload(0);

  for (int t = 0; t < 12; t++){
    __syncthreads();
    #pragma unroll
    for (int i = 0; i < 8; i++){
      int idx = tid + i*256, r = idx >> 5, g = idx & 31;
      *(bf16x8*)(Ws + r*256 + ((g ^ (r & 7))*8)) = wreg[i];
    }
    __syncthreads();
    if (t < 11) preload(t+1);

    f32x4 acc[2][2] = {};
    #pragma unroll
    for (int kk = 0; kk < 8; kk++){
      int off = ((kk*4 + lg) ^ (lr & 7)) * 8;
      bf16x8 a0 = *(const bf16x8*)(Xs + (wr +      lr)*256 + off);
      bf16x8 a1 = *(const bf16x8*)(Xs + (wr + 16 + lr)*256 + off);
      bf16x8 b0 = *(const bf16x8*)(Ws + (wc +      lr)*256 + off);
      bf16x8 b1 = *(const bf16x8*)(Ws + (wc + 16 + lr)*256 + off);
      acc[0][0] = MFMA(a0, b0, acc[0][0]);
      acc[0][1] = MFMA(a0, b1, acc[0][1]);
      acc[1][0] = MFMA(a1, b0, acc[1][0]);
      acc[1][1] = MFMA(a1, b1, acc[1][1]);
    }
    int w = t >> 2, c0t = (t & 3) * 64;
    const uint16_t* bias = (w == 0) ? bq : ((w == 1) ? bk : bv);
    uint16_t* O = (w == 0) ? Oq : ((w == 1) ? Ok : Ov);
    #pragma unroll
    for (int i = 0; i < 2; i++)
    #pragma unroll
    for (int j = 0; j < 2; j++){
      int col = c0t + wc + j*16 + lr;
      float bvv = bf2f(bias[col]);
      #pragma unroll
      for (int rr = 0; rr < 4; rr++){
        int row = r0 + wr + i*16 + lg*4 + rr;
        O[(size_t)row*DHID + col] = f2bf(acc[i][j][rr] + bvv);
      }
    }
  }
}

// ---------------- K2 v4 (R12 exact): attention, half-P streaming, 3 blocks/CU ----------------
__global__ __launch_bounds__(256) void k_attn(
    const uint16_t* __restrict__ Q, const uint16_t* __restrict__ Kb, const uint16_t* __restrict__ V,
    const unsigned long long* __restrict__ packed, uint16_t* __restrict__ ctx)
{
  extern __shared__ uint16_t sm[];
  uint16_t* Ks = sm;              // [128][64]  swizzled
  uint16_t* Vt = sm + 8192;       // [64][128]  V transposed, swizzled
  uint16_t* Ph = sm + 16384;      // [128][64]  half-P, swizzled
  unsigned long long* Ms = (unsigned long long*)(sm + 24576);   // [128][2]
  const int b = blockIdx.x >> 2;
  const int h = blockIdx.x & 3;
  const int tid = threadIdx.x, lane = tid & 63, wav = tid >> 6;
  const int lr = lane & 15, lg = lane >> 4;
  const size_t base = ((size_t)b * NTOK) * DHID + h * DHEAD;

  Ms[tid] = packed[(size_t)b*NTOK*2 + tid];
  #pragma unroll
  for (int i = 0; i < 4; i++){
    int c = tid + i*256;
    int row = c >> 3, g = c & 7;
    *(bf16x8*)(Ks + row*64 + (g ^ (row & 7))*8) =
        *(const bf16x8*)(Kb + base + (size_t)row*DHID + g*8);
  }
  #pragma unroll
  for (int i = 0; i < 4; i++){
    int c = tid + i*256;
    int n = c & 127, d8 = (c >> 7) * 8;
    bf16x8 v = *(const bf16x8*)(V + base + (size_t)n*DHID + d8);
    #pragma unroll
    for (int e = 0; e < 8; e++){
      int d = d8 + e;
      Vt[d*128 + ((n >> 3) ^ (d & 7))*8 + (n & 7)] = (uint16_t)v[e];
    }
  }
  __syncthreads();

  const int qrow0 = wav * 32;
  bf16x8 qf[2][2];
  #pragma unroll
  for (int i = 0; i < 2; i++)
  #pragma unroll
  for (int kk = 0; kk < 2; kk++)
    qf[i][kk] = *(const bf16x8*)(Q + base + (size_t)(qrow0 + i*16 + lr)*DHID + kk*32 + lg*8);

  f32x4 sa[2][8] = {};
  #pragma unroll
  for (int kk = 0; kk < 2; kk++){
    int off = ((kk*4 + lg) ^ (lr & 7)) * 8;
    #pragma unroll
    for (int j = 0; j < 8; j++){
      bf16x8 bf = *(const bf16x8*)(Ks + (j*16 + lr)*64 + off);
      sa[0][j] = MFMA(qf[0][kk], bf, sa[0][j]);
      sa[1][j] = MFMA(qf[1][kk], bf, sa[1][j]);
    }
  }
  float iv[2][4];
  #pragma unroll
  for (int i = 0; i < 2; i++){
    #pragma unroll
    for (int rr = 0; rr < 4; rr++){
      int n = qrow0 + i*16 + lg*4 + rr;
      unsigned long long m0 = Ms[n*2 + 0];
      unsigned long long m1 = Ms[n*2 + 1];
      float sv[8];
      float mx = -3.0e38f;
      #pragma unroll
      for (int j = 0; j < 8; j++){
        int col = j*16 + lr;
        unsigned long long w = (col < 64) ? m0 : m1;
        float s = sa[i][j][rr] * 0.125f;
        sv[j] = ((w >> (col & 63)) & 1ull) ? s : -1e9f;
        mx = fmaxf(mx, sv[j]);
      }
      mx = fmaxf(mx, __shfl_xor(mx, 1));
      mx = fmaxf(mx, __shfl_xor(mx, 2));
      mx = fmaxf(mx, __shfl_xor(mx, 4));
      mx = fmaxf(mx, __shfl_xor(mx, 8));
      float sum = 0.f;
      #pragma unroll
      for (int j = 0; j < 8; j++){ sv[j] = __expf(sv[j] - mx); sum += sv[j]; }
      sum += __shfl_xor(sum, 1);
      sum += __shfl_xor(sum, 2);
      sum += __shfl_xor(sum, 4);
      sum += __shfl_xor(sum, 8);
      iv[i][rr] = __builtin_amdgcn_rcpf(sum);
      #pragma unroll
      for (int j = 0; j < 8; j++) sa[i][j][rr] = sv[j];
    }
  }

  f32x4 oa[2][4] = {};
  #pragma unroll
  for (int half = 0; half < 2; half++){
    #pragma unroll
    for (int i = 0; i < 2; i++)
    #pragma unroll
    for (int j = 0; j < 4; j++){
      int ch = j*16 + lr;
      #pragma unroll
      for (int rr = 0; rr < 4; rr++){
        int n = qrow0 + i*16 + lg*4 + rr;
        Ph[n*64 + ((ch>>3) ^ (n&7))*8 + (ch&7)] = f2bf(sa[i][half*4 + j][rr]);
      }
    }
    #pragma unroll
    for (int kkl = 0; kkl < 2; kkl++){
      int offA = ((kkl*4 + lg) ^ (lr & 7)) * 8;
      int kk = half*2 + kkl;
      int offB = ((kk*4 + lg) ^ (lr & 7)) * 8;
      bf16x8 a0 = *(const bf16x8*)(Ph + (qrow0 +      lr)*64 + offA);
      bf16x8 a1 = *(const bf16x8*)(Ph + (qrow0 + 16 + lr)*64 + offA);
      #pragma unroll
      for (int j = 0; j < 4; j++){
        bf16x8 bf = *(const bf16x8*)(Vt + (j*16 + lr)*128 + offB);
        oa[0][j] = MFMA(a0, bf, oa[0][j]);
        oa[1][j] = MFMA(a1, bf, oa[1][j]);
      }
    }
  }
  #pragma unroll
  for (int i = 0; i < 2; i++)
  #pragma unroll
  for (int j = 0; j < 4; j++)
  #pragma unroll
  for (int rr = 0; rr < 4; rr++){
    int n = qrow0 + i*16 + lg*4 + rr;
    ctx[((size_t)b*NTOK + n)*DHID + h*DHEAD + j*16 + lr] = f2bf(oa[i][j][rr] * iv[i][rr]);
  }
}

// ---------------- K3 v9: fused Wo/GRU, 256 rows/block, 8 waves, single Wb ----------------
// 512 thr = 8 waves; wave owns 32 rows (same per-thread state as v8 -> VGPR ~112).
// Weight slice staged once per 256 rows (2x amortization); branch-free staging:
// granules 0..1535 = Whh (3 x 512 uniform), 1536..1919 = Wih (tail, waves 0-5).
// LDS: Wb 15360 + Is[256][64] 16384 + bias 1536 = 33280 elems = 66560 B -> 2 blocks/CU.
// Schedule/cs: MFMAs(read Wb) -> barrier1 -> stage(cs+1) -> epilogue(no Wb) -> barrier2.
__global__ __launch_bounds__(512, 2) void k_gru(
    const uint16_t* __restrict__ ctxp, const uint16_t* __restrict__ lat,
    const uint16_t* __restrict__ Wo, const uint16_t* __restrict__ Wih, const uint16_t* __restrict__ Whh,
    const uint16_t* __restrict__ bih, const uint16_t* __restrict__ bhh,
    const unsigned char* __restrict__ upd, uint16_t* __restrict__ Lbuf,
    uint16_t* __restrict__ dout, const uint32_t* __restrict__ flag, int layer)
{
  extern __shared__ uint16_t sm[];
  uint16_t* Wb    = sm;              // 1920 granules * 8 = 15360 elems
  uint16_t* Is    = sm + 15360;      // [256][64] swizzled
  uint16_t* biasS = sm + 31744;      // 1536
  uint16_t* lat_out = (layer == 1 && *flag) ? dout : Lbuf;
  const int r0 = blockIdx.x * 256;
  const int tid = threadIdx.x, lane = tid & 63, wav = tid >> 6;
  const int lr = lane & 15, lg = lane >> 4;
  const int wrow = wav * 32;

  #pragma unroll
  for (int i = 0; i < 3; i++){
    int idx = tid + i*512;
    if (idx < 1536) biasS[idx] = (idx < 768) ? bih[idx] : bhh[idx - 768];
  }

  auto stage_async = [&](int cs){
    #pragma unroll
    for (int c = 0; c < 3; c++){               // Whh granules 0..1535, uniform
      int G = c*512 + tid;
      int r = G >> 5, gp = G & 31;
      const uint16_t* src = Whh + (size_t)((r>>4)*256 + cs*16 + (r&15))*DHID + (gp ^ (r&7))*8;
      __builtin_amdgcn_global_load_lds(
          (const __attribute__((address_space(1))) uint32_t*)src,
          (__attribute__((address_space(3))) uint32_t*)(Wb + (size_t)G*8),
          16, 0, 0);
    }
    if (tid < 384){                            // Wih granules 1536..1919, waves 0-5
      int G = 1536 + tid;
      int G2 = tid, r = G2 >> 3, gp = G2 & 7;
      const uint16_t* src = Wih + (size_t)((r>>4)*256 + cs*16 + (r&15))*DHEAD + (gp ^ (r&7))*8;
      __builtin_amdgcn_global_load_lds(
          (const __attribute__((address_space(1))) uint32_t*)src,
          (__attribute__((address_space(3))) uint32_t*)(Wb + (size_t)G*8),
          16, 0, 0);
    }
  };

  stage_async(0);

  // ---- phase A: info = ctx @ Wo^T (2 tiles/wave) — overlaps DMA(0) ----
  f32x4 ai[2][4] = {};
  #pragma unroll
  for (int kk = 0; kk < 8; kk++){
    bf16x8 bw[4];
    #pragma unroll
    for (int j = 0; j < 4; j++)
      bw[j] = *(const bf16x8*)(Wo + (size_t)(j*16 + lr)*DHID + kk*32 + lg*8);
    #pragma unroll
    for (int t = 0; t < 2; t++){
      bf16x8 ac = *(const bf16x8*)(ctxp + (size_t)(r0 + wrow + t*16 + lr)*DHID + kk*32 + lg*8);
      #pragma unroll
      for (int j = 0; j < 4; j++) ai[t][j] = MFMA(ac, bw[j], ai[t][j]);
    }
  }
  #pragma unroll
  for (int t = 0; t < 2; t++)
  #pragma unroll
  for (int j = 0; j < 4; j++)
  #pragma unroll
  for (int rr = 0; rr < 4; rr++){
    int row = wrow + t*16 + lg*4 + rr, col = j*16 + lr;
    Is[row*64 + ((col>>3) ^ (row&7))*8 + (col&7)] = f2bf(ai[t][j][rr]);
  }

  bf16x8 aL[2][8];
  #pragma unroll
  for (int t = 0; t < 2; t++)
  #pragma unroll
  for (int kk = 0; kk < 8; kk++)
    aL[t][kk] = *(const bf16x8*)(lat + (size_t)(r0 + wrow + t*16 + lr)*DHID + kk*32 + lg*8);

  uint32_t u4[2];
  #pragma unroll
  for (int t = 0; t < 2; t++)
    u4[t] = *(const uint32_t*)(upd + r0 + wrow + t*16 + lg*4);

  __syncthreads();     // drains DMA(0); Is, bias ready

  const float LOG2E = 1.44269504f;
  for (int cs = 0; cs < 16; cs++){
    const uint16_t* WhhS = Wb;
    const uint16_t* WihS = Wb + 12288;

    f32x4 arz[2][2] = {};
    f32x4 gin[2] = {}, ghn[2] = {};

    #pragma unroll
    for (int kk = 0; kk < 2; kk++){
      int off = ((kk*4 + lg) ^ (lr & 7)) * 8;
      bf16x8 br = *(const bf16x8*)(WihS + (0*16 + lr)*64 + off);
      bf16x8 bz = *(const bf16x8*)(WihS + (1*16 + lr)*64 + off);
      bf16x8 bn = *(const bf16x8*)(WihS + (2*16 + lr)*64 + off);
      #pragma unroll
      for (int t = 0; t < 2; t++){
        bf16x8 a = *(const bf16x8*)(Is + (wrow + t*16 + lr)*64 + off);
        arz[0][t] = MFMA(a, br, arz[0][t]);
        arz[1][t] = MFMA(a, bz, arz[1][t]);
        gin[t]    = MFMA(a, bn, gin[t]);
      }
    }
    #pragma unroll
    for (int kk = 0; kk < 8; kk++){
      int off = ((kk*4 + lg) ^ (lr & 7)) * 8;
      bf16x8 br = *(const bf16x8*)(WhhS + (0*16 + lr)*256 + off);
      bf16x8 bz = *(const bf16x8*)(WhhS + (1*16 + lr)*256 + off);
      bf16x8 bn = *(const bf16x8*)(WhhS + (2*16 + lr)*256 + off);
      #pragma unroll
      for (int t = 0; t < 2; t++){
        arz[0][t] = MFMA(aL[t][kk], br, arz[0][t]);
        arz[1][t] = MFMA(aL[t][kk], bz, arz[1][t]);
        ghn[t]    = MFMA(aL[t][kk], bn, ghn[t]);
      }
    }

    __syncthreads();                 // barrier 1: all waves done reading Wb
    if (cs < 15) stage_async(cs+1);  // DMA lands during epilogue

    int col = cs*16 + lr;
    float brz0 = bf2f(biasS[col])     + bf2f(biasS[768+col]);
    float brz1 = bf2f(biasS[256+col]) + bf2f(biasS[1024+col]);
    float bin_ = bf2f(biasS[512+col]);
    float bhn  = bf2f(biasS[1280+col]);
    #pragma unroll
    for (int t = 0; t < 2; t++)
    #pragma unroll
    for (int rr = 0; rr < 4; rr++){
      int row = wrow + t*16 + lg*4 + rr;
      float hv = bf2f(lat[(size_t)(r0+row)*DHID + col]);
      float xr = arz[0][t][rr] + brz0;
      float xz = arz[1][t][rr] + brz1;
      float rg = __builtin_amdgcn_rcpf(1.f + __builtin_amdgcn_exp2f(-xr*LOG2E));
      float zg = __builtin_amdgcn_rcpf(1.f + __builtin_amdgcn_exp2f(-xz*LOG2E));
      float nx = (gin[t][rr] + bin_) + rg*(ghn[t][rr] + bhn);
      nx = fminf(10.f, fmaxf(-10.f, nx));
      float e2 = __builtin_amdgcn_exp2f(-2.f*LOG2E*nx);
      float ng = (1.f - e2) * __builtin_amdgcn_rcpf(1.f + e2);
      float hp = (1.f - zg)*ng + zg*hv;
      float ov = ((u4[t] >> (rr*8)) & 1u) ? hp : hv;
      lat_out[(size_t)(r0+row)*DHID + col] = f2bf(ov);
    }
    if (cs < 15) __syncthreads();    // barrier 2: drains DMA before next reads
  }
}

extern "C" void kernel_launch(void* const* d_in, const int* in_sizes, int n_in,
                              void* d_out, int out_size, void* d_ws, size_t ws_size,
                              hipStream_t stream)
{
  (void)in_sizes; (void)n_in; (void)out_size;
  const void* latent = d_in[0];
  const int*  mask   = (const int*)d_in[1];
  const void* Wq  = d_in[3]; const void* bq  = d_in[4];
  const void* Wk  = d_in[5]; const void* bk  = d_in[6];
  const void* Wv  = d_in[7]; const void* bv  = d_in[8];
  const void* Wo  = d_in[9];
  const void* Wih = d_in[10]; const void* Whh = d_in[11];
  const void* bih = d_in[12]; const void* bhh = d_in[13];

  uint8_t* p = (uint8_t*)d_ws;
  uint32_t* flag = (uint32_t*)p;            p += 256;
  uint16_t* Wqc  = (uint16_t*)p;            p += 65536*2;
  uint16_t* Wkc  = (uint16_t*)p;            p += 65536*2;
  uint16_t* Wvc  = (uint16_t*)p;            p += 65536*2;
  uint16_t* Woc  = (uint16_t*)p;            p += 16384*2;
  uint16_t* Wihc = (uint16_t*)p;            p += 49152*2;
  uint16_t* Whhc = (uint16_t*)p;            p += 196608*2;
  uint16_t* bqc  = (uint16_t*)p;            p += 512;
  uint16_t* bkc  = (uint16_t*)p;            p += 512;
  uint16_t* bvc  = (uint16_t*)p;            p += 512;
  uint16_t* bihc = (uint16_t*)p;            p += 1536;
  uint16_t* bhhc = (uint16_t*)p;            p += 1536;
  uint8_t* chunk0 = p;
  size_t reserved = (size_t)(chunk0 - (uint8_t*)d_ws);
  const size_t perb = 5ull*65536 + 2048 + 128;

  const int Btot = 1024;
  int CB = (int)((ws_size > reserved ? ws_size - reserved : 0) / perb);
  if (CB > Btot) CB = Btot;
  CB &= ~1;                      // k_gru blocks cover 256 rows = 2 batches
  if (CB < 2) CB = 2;

  auto cgrid = [](int n){ int b = (n/8 + 255)/256; if (b > 2048) b = 2048; if (b < 1) b = 1; return (unsigned)b; };

  k_detect<<<1, 64, 0, stream>>>((const uint32_t*)latent, flag);
  k_convw<<<225, 256, 0, stream>>>(flag, Wq, Wk, Wv, Wo, Wih, Whh,
                                   bq, bk, bv, bih, bhh, Wqc);

  for (int b0 = 0; b0 < Btot; b0 += CB){
    int cb = (Btot - b0 < CB) ? (Btot - b0) : CB;
    int rows = cb * 128;
    int nelem = rows * DHID;
    uint8_t* q = chunk0;
    uint16_t* L    = (uint16_t*)q; q += (size_t)cb*65536;
    uint16_t* q_ws = (uint16_t*)q; q += (size_t)cb*65536;
    uint16_t* k_ws = (uint16_t*)q; q += (size_t)cb*65536;
    uint16_t* v_ws = (uint16_t*)q; q += (size_t)cb*65536;
    uint16_t* c_ws = (uint16_t*)q; q += (size_t)cb*65536;
    unsigned long long* packed = (unsigned long long*)q; q += (size_t)cb*2048;
    unsigned char* updp = (unsigned char*)q;

    uint16_t* dout_b = (uint16_t*)d_out + (size_t)b0*NTOK*DHID;   // bf16 view

    k_conv<<<cgrid(nelem), 256, 0, stream>>>(latent, (unsigned long long)b0*NTOK*DHID, L, flag, nelem);
    k_maskpack<<<dim3(rows/4), 256, 0, stream>>>(mask + (size_t)b0*NTOK*NTOK, packed, updp, rows);

    for (int layer = 0; layer < 2; layer++){
      k_qkv <<<dim3(rows/64),  256, 65536, stream>>>(L, Wqc,bqc, Wkc,bkc, Wvc,bvc, q_ws, k_ws, v_ws);
      k_attn<<<dim3(cb*NHEAD), 256, 51200, stream>>>(q_ws, k_ws, v_ws, packed, c_ws);
      k_gru <<<dim3(rows/256), 512, 66560, stream>>>(c_ws, L, Woc, Wihc, Whhc, bihc, bhhc, updp,
                                                     L, dout_b, flag, layer);
    }
    k_store<<<cgrid(nelem), 256, 0, stream>>>(L, (void*)((float*)d_out + (size_t)b0*NTOK*DHID), 0, flag, nelem);
  }
}

// Round 16
// 682.181 us; speedup vs baseline: 1.0417x; 1.0417x over previous
//
#include <hip/hip_runtime.h>
#include <stdint.h>

#define NTOK 128
#define DHID 256
#define NHEAD 4
#define DHEAD 64

typedef short bf16x8 __attribute__((ext_vector_type(8)));
typedef float f32x4 __attribute__((ext_vector_type(4)));

#define MFMA(a,b,c) __builtin_amdgcn_mfma_f32_16x16x32_bf16((a),(b),(c),0,0,0)

__device__ __forceinline__ float bf2f(uint16_t u){
  union { uint32_t i; float f; } v; v.i = ((uint32_t)u) << 16; return v.f;
}
__device__ __forceinline__ uint16_t f2bf(float f){
  union { uint32_t i; float f; } v; v.f = f;
  uint32_t i = v.i + 0x7FFFu + ((v.i >> 16) & 1u);
  return (uint16_t)(i >> 16);
}

// ---------------- dtype probe ----------------
__global__ void k_detect(const uint32_t* __restrict__ raw, uint32_t* __restrict__ flag){
  int lane = threadIdx.x;
  int hits = 0;
  #pragma unroll
  for (int i = 0; i < 16; i++){
    uint32_t w = raw[lane*16 + i];
    uint32_t e = (w >> 7) & 0xFFu;
    hits += (e >= 0x70u && e <= 0x8Fu) ? 1 : 0;
  }
  #pragma unroll
  for (int m = 1; m < 64; m <<= 1) hits += __shfl_xor(hits, m);
  if (lane == 0) *flag = (hits > 512) ? 1u : 0u;   // 1 = bf16, 0 = fp32
}

// ---------------- merged weight conversion (fp32 path only) ----------------
__global__ __launch_bounds__(256) void k_convw(const uint32_t* __restrict__ flag,
    const void* Wq, const void* Wk, const void* Wv, const void* Wo,
    const void* Wih, const void* Whh,
    const void* bq, const void* bk, const void* bv, const void* bih, const void* bhh,
    uint16_t* __restrict__ dst)
{
  if (*flag) return;
  int blk = blockIdx.x, tid = threadIdx.x;
  if (blk < 224){
    const float* src; size_t doff; int so;
    if      (blk <  32){ src = (const float*)Wq;  doff = 0;      so = blk*2048; }
    else if (blk <  64){ src = (const float*)Wk;  doff = 65536;  so = (blk-32)*2048; }
    else if (blk <  96){ src = (const float*)Wv;  doff = 131072; so = (blk-64)*2048; }
    else if (blk < 104){ src = (const float*)Wo;  doff = 196608; so = (blk-96)*2048; }
    else if (blk < 128){ src = (const float*)Wih; doff = 212992; so = (blk-104)*2048; }
    else               { src = (const float*)Whh; doff = 262144; so = (blk-128)*2048; }
    int i = so + tid*8;
    float4 a = *(const float4*)(src + i);
    float4 b = *(const float4*)(src + i + 4);
    uint16_t o[8] = {f2bf(a.x),f2bf(a.y),f2bf(a.z),f2bf(a.w),
                     f2bf(b.x),f2bf(b.y),f2bf(b.z),f2bf(b.w)};
    *(bf16x8*)(dst + doff + i) = *(const bf16x8*)o;
  } else {
    for (int i = tid; i < 2304; i += 256){
      const float* s; int lo;
      if      (i <  256){ s = (const float*)bq;  lo = i; }
      else if (i <  512){ s = (const float*)bk;  lo = i - 256; }
      else if (i <  768){ s = (const float*)bv;  lo = i - 512; }
      else if (i < 1536){ s = (const float*)bih; lo = i - 768; }
      else              { s = (const float*)bhh; lo = i - 1536; }
      dst[458752 + i] = f2bf(s[lo]);
    }
  }
}

// ---------------- normalize latent to bf16 (both paths; bf16 = copy) ----------------
__global__ void k_conv(const void* __restrict__ src, unsigned long long off,
                       uint16_t* __restrict__ dst, const uint32_t* __restrict__ flag, int n){
  const int isbf = (int)*flag;
  int i0 = (blockIdx.x * blockDim.x + threadIdx.x) * 8;
  int stride = gridDim.x * blockDim.x * 8;
  if (isbf){
    const uint16_t* s = (const uint16_t*)src + off;
    for (int i = i0; i < n; i += stride)
      *(bf16x8*)(dst + i) = *(const bf16x8*)(s + i);
  } else {
    const float* s = (const float*)src + off;
    for (int i = i0; i < n; i += stride){
      float4 a = *(const float4*)(s + i);
      float4 b = *(const float4*)(s + i + 4);
      uint16_t o[8] = {f2bf(a.x),f2bf(a.y),f2bf(a.z),f2bf(a.w),
                       f2bf(b.x),f2bf(b.y),f2bf(b.z),f2bf(b.w)};
      *(bf16x8*)(dst + i) = *(const bf16x8*)o;
    }
  }
}

// ---------------- store result (fp32 path only; bf16 path: gru wrote d_out) ----------------
__global__ void k_store(const uint16_t* __restrict__ L, void* __restrict__ dst,
                        unsigned long long off, const uint32_t* __restrict__ flag, int n){
  if (*flag) return;
  int i0 = (blockIdx.x * blockDim.x + threadIdx.x) * 8;
  int stride = gridDim.x * blockDim.x * 8;
  float* d = (float*)dst + off;
  for (int i = i0; i < n; i += stride){
    bf16x8 v = *(const bf16x8*)(L + i);
    #pragma unroll
    for (int e = 0; e < 8; e++) d[i + e] = bf2f((uint16_t)v[e]);
  }
}

// ---------------- K0: pack mask rows ----------------
__global__ __launch_bounds__(256) void k_maskpack(const int* __restrict__ mask,
                                                  unsigned long long* __restrict__ packed,
                                                  unsigned char* __restrict__ upd, int nrows){
  int row = blockIdx.x * 4 + (threadIdx.x >> 6);
  if (row >= nrows) return;
  int lane = threadIdx.x & 63;
  const int* mrow = mask + (size_t)row * NTOK;
  unsigned long long b0 = __ballot(mrow[lane] != 0);
  unsigned long long b1 = __ballot(mrow[lane + 64] != 0);
  if (lane == 0){
    packed[row*2 + 0] = b0;
    packed[row*2 + 1] = b1;
    upd[row] = (unsigned char)((__popcll(b0) + __popcll(b1)) > 1 ? 1 : 0);
  }
}

// ---------------- K1 (R6 exact): QKV — stage X once, loop 12 weight tiles ----------------
__global__ __launch_bounds__(256) void k_qkv(
    const uint16_t* __restrict__ X,
    const uint16_t* __restrict__ Wq, const uint16_t* __restrict__ bq,
    const uint16_t* __restrict__ Wk, const uint16_t* __restrict__ bk,
    const uint16_t* __restrict__ Wv, const uint16_t* __restrict__ bv,
    uint16_t* __restrict__ Oq, uint16_t* __restrict__ Ok, uint16_t* __restrict__ Ov)
{
  extern __shared__ uint16_t sm[];
  uint16_t* Xs = sm;            // [64][256] swizzled
  uint16_t* Ws = sm + 64*256;   // [64][256] swizzled (per weight tile)
  const int r0 = blockIdx.x * 64;
  const int tid = threadIdx.x;
  const int lane = tid & 63, lr = lane & 15, lg = lane >> 4;
  const int wav = tid >> 6;
  const int wr = (wav >> 1) * 32, wc = (wav & 1) * 32;

  #pragma unroll
  for (int i = 0; i < 8; i++){
    int c = tid + i*256, row = c >> 5, g = c & 31;
    *(bf16x8*)(Xs + row*256 + (g ^ (row & 7))*8) =
        *(const bf16x8*)(X + (size_t)(r0+row)*DHID + g*8);
  }

  bf16x8 wreg[8];
  auto wptr = [&](int t)->const uint16_t*{
    int w = t >> 2;
    return (w == 0) ? Wq : ((w == 1) ? Wk : Wv);
  };
  auto preload = [&](int t){
    const uint16_t* W = wptr(t);
    int c0t = (t & 3) * 64;
    #pragma unroll
    for (int i = 0; i < 8; i++){
      int idx = tid + i*256, r = idx >> 5, g = idx & 31;
      wreg[i] = *(const bf16x8*)(W + (size_t)(c0t + r)*DHID + g*8);
    }
  };
  preload(0);

  for (int t = 0; t < 12; t++){
    __syncthreads();
    #pragma unroll
    for (int i = 0; i < 8; i++){
      int idx = tid + i*256, r = idx >> 5, g = idx & 31;
      *(bf16x8*)(Ws + r*256 + ((g ^ (r & 7))*8)) = wreg[i];
    }
    __syncthreads();
    if (t < 11) preload(t+1);

    f32x4 acc[2][2] = {};
    #pragma unroll
    for (int kk = 0; kk < 8; kk++){
      int off = ((kk*4 + lg) ^ (lr & 7)) * 8;
      bf16x8 a0 = *(const bf16x8*)(Xs + (wr +      lr)*256 + off);
      bf16x8 a1 = *(const bf16x8*)(Xs + (wr + 16 + lr)*256 + off);
      bf16x8 b0 = *(const bf16x8*)(Ws + (wc +      lr)*256 + off);
      bf16x8 b1 = *(const bf16x8*)(Ws + (wc + 16 + lr)*256 + off);
      acc[0][0] = MFMA(a0, b0, acc[0][0]);
      acc[0][1] = MFMA(a0, b1, acc[0][1]);
      acc[1][0] = MFMA(a1, b0, acc[1][0]);
      acc[1][1] = MFMA(a1, b1, acc[1][1]);
    }
    int w = t >> 2, c0t = (t & 3) * 64;
    const uint16_t* bias = (w == 0) ? bq : ((w == 1) ? bk : bv);
    uint16_t* O = (w == 0) ? Oq : ((w == 1) ? Ok : Ov);
    #pragma unroll
    for (int i = 0; i < 2; i++)
    #pragma unroll
    for (int j = 0; j < 2; j++){
      int col = c0t + wc + j*16 + lr;
      float bvv = bf2f(bias[col]);
      #pragma unroll
      for (int rr = 0; rr < 4; rr++){
        int row = r0 + wr + i*16 + lg*4 + rr;
        O[(size_t)row*DHID + col] = f2bf(acc[i][j][rr] + bvv);
      }
    }
  }
}

// ---------------- K2 v4 (R12 exact): attention, half-P streaming, 3 blocks/CU ----------------
__global__ __launch_bounds__(256) void k_attn(
    const uint16_t* __restrict__ Q, const uint16_t* __restrict__ Kb, const uint16_t* __restrict__ V,
    const unsigned long long* __restrict__ packed, uint16_t* __restrict__ ctx)
{
  extern __shared__ uint16_t sm[];
  uint16_t* Ks = sm;              // [128][64]  swizzled
  uint16_t* Vt = sm + 8192;       // [64][128]  V transposed, swizzled
  uint16_t* Ph = sm + 16384;      // [128][64]  half-P, swizzled
  unsigned long long* Ms = (unsigned long long*)(sm + 24576);   // [128][2]
  const int b = blockIdx.x >> 2;
  const int h = blockIdx.x & 3;
  const int tid = threadIdx.x, lane = tid & 63, wav = tid >> 6;
  const int lr = lane & 15, lg = lane >> 4;
  const size_t base = ((size_t)b * NTOK) * DHID + h * DHEAD;

  Ms[tid] = packed[(size_t)b*NTOK*2 + tid];
  #pragma unroll
  for (int i = 0; i < 4; i++){
    int c = tid + i*256;
    int row = c >> 3, g = c & 7;
    *(bf16x8*)(Ks + row*64 + (g ^ (row & 7))*8) =
        *(const bf16x8*)(Kb + base + (size_t)row*DHID + g*8);
  }
  #pragma unroll
  for (int i = 0; i < 4; i++){
    int c = tid + i*256;
    int n = c & 127, d8 = (c >> 7) * 8;
    bf16x8 v = *(const bf16x8*)(V + base + (size_t)n*DHID + d8);
    #pragma unroll
    for (int e = 0; e < 8; e++){
      int d = d8 + e;
      Vt[d*128 + ((n >> 3) ^ (d & 7))*8 + (n & 7)] = (uint16_t)v[e];
    }
  }
  __syncthreads();

  const int qrow0 = wav * 32;
  bf16x8 qf[2][2];
  #pragma unroll
  for (int i = 0; i < 2; i++)
  #pragma unroll
  for (int kk = 0; kk < 2; kk++)
    qf[i][kk] = *(const bf16x8*)(Q + base + (size_t)(qrow0 + i*16 + lr)*DHID + kk*32 + lg*8);

  f32x4 sa[2][8] = {};
  #pragma unroll
  for (int kk = 0; kk < 2; kk++){
    int off = ((kk*4 + lg) ^ (lr & 7)) * 8;
    #pragma unroll
    for (int j = 0; j < 8; j++){
      bf16x8 bf = *(const bf16x8*)(Ks + (j*16 + lr)*64 + off);
      sa[0][j] = MFMA(qf[0][kk], bf, sa[0][j]);
      sa[1][j] = MFMA(qf[1][kk], bf, sa[1][j]);
    }
  }
  float iv[2][4];
  #pragma unroll
  for (int i = 0; i < 2; i++){
    #pragma unroll
    for (int rr = 0; rr < 4; rr++){
      int n = qrow0 + i*16 + lg*4 + rr;
      unsigned long long m0 = Ms[n*2 + 0];
      unsigned long long m1 = Ms[n*2 + 1];
      float sv[8];
      float mx = -3.0e38f;
      #pragma unroll
      for (int j = 0; j < 8; j++){
        int col = j*16 + lr;
        unsigned long long w = (col < 64) ? m0 : m1;
        float s = sa[i][j][rr] * 0.125f;
        sv[j] = ((w >> (col & 63)) & 1ull) ? s : -1e9f;
        mx = fmaxf(mx, sv[j]);
      }
      mx = fmaxf(mx, __shfl_xor(mx, 1));
      mx = fmaxf(mx, __shfl_xor(mx, 2));
      mx = fmaxf(mx, __shfl_xor(mx, 4));
      mx = fmaxf(mx, __shfl_xor(mx, 8));
      float sum = 0.f;
      #pragma unroll
      for (int j = 0; j < 8; j++){ sv[j] = __expf(sv[j] - mx); sum += sv[j]; }
      sum += __shfl_xor(sum, 1);
      sum += __shfl_xor(sum, 2);
      sum += __shfl_xor(sum, 4);
      sum += __shfl_xor(sum, 8);
      iv[i][rr] = __builtin_amdgcn_rcpf(sum);
      #pragma unroll
      for (int j = 0; j < 8; j++) sa[i][j][rr] = sv[j];
    }
  }

  f32x4 oa[2][4] = {};
  #pragma unroll
  for (int half = 0; half < 2; half++){
    #pragma unroll
    for (int i = 0; i < 2; i++)
    #pragma unroll
    for (int j = 0; j < 4; j++){
      int ch = j*16 + lr;
      #pragma unroll
      for (int rr = 0; rr < 4; rr++){
        int n = qrow0 + i*16 + lg*4 + rr;
        Ph[n*64 + ((ch>>3) ^ (n&7))*8 + (ch&7)] = f2bf(sa[i][half*4 + j][rr]);
      }
    }
    #pragma unroll
    for (int kkl = 0; kkl < 2; kkl++){
      int offA = ((kkl*4 + lg) ^ (lr & 7)) * 8;
      int kk = half*2 + kkl;
      int offB = ((kk*4 + lg) ^ (lr & 7)) * 8;
      bf16x8 a0 = *(const bf16x8*)(Ph + (qrow0 +      lr)*64 + offA);
      bf16x8 a1 = *(const bf16x8*)(Ph + (qrow0 + 16 + lr)*64 + offA);
      #pragma unroll
      for (int j = 0; j < 4; j++){
        bf16x8 bf = *(const bf16x8*)(Vt + (j*16 + lr)*128 + offB);
        oa[0][j] = MFMA(a0, bf, oa[0][j]);
        oa[1][j] = MFMA(a1, bf, oa[1][j]);
      }
    }
  }
  #pragma unroll
  for (int i = 0; i < 2; i++)
  #pragma unroll
  for (int j = 0; j < 4; j++)
  #pragma unroll
  for (int rr = 0; rr < 4; rr++){
    int n = qrow0 + i*16 + lg*4 + rr;
    ctx[((size_t)b*NTOK + n)*DHID + h*DHEAD + j*16 + lr] = f2bf(oa[i][j][rr] * iv[i][rr]);
  }
}

// ---------------- K3 v8 (R14 exact): fused Wo/GRU, single Wb, DMA under epilogue ----------------
// LDS: Wb 15360 + Is 8192 + bias 1536 = 25088 elems = 50176 B.
// Schedule/cs: MFMAs(read Wb) -> barrier1 -> stage(cs+1) -> epilogue(no Wb) -> barrier2.
__global__ __launch_bounds__(256, 2) void k_gru(
    const uint16_t* __restrict__ ctxp, const uint16_t* __restrict__ lat,
    const uint16_t* __restrict__ Wo, const uint16_t* __restrict__ Wih, const uint16_t* __restrict__ Whh,
    const uint16_t* __restrict__ bih, const uint16_t* __restrict__ bhh,
    const unsigned char* __restrict__ upd, uint16_t* __restrict__ Lbuf,
    uint16_t* __restrict__ dout, const uint32_t* __restrict__ flag, int layer)
{
  extern __shared__ uint16_t sm[];
  uint16_t* Wb    = sm;              // 1920 granules * 8 = 15360 elems
  uint16_t* Is    = sm + 15360;      // [128][64] swizzled
  uint16_t* biasS = sm + 23552;      // 1536
  uint16_t* lat_out = (layer == 1 && *flag) ? dout : Lbuf;
  const int r0 = blockIdx.x * 128;
  const int tid = threadIdx.x, lane = tid & 63, wav = tid >> 6;
  const int lr = lane & 15, lg = lane >> 4;
  const int wrow = wav * 32;

  #pragma unroll
  for (int i = 0; i < 6; i++){
    int idx = tid + i*256;
    if (idx < 1536) biasS[idx] = (idx < 768) ? bih[idx] : bhh[idx - 768];
  }

  auto stage_async = [&](int cs){
    #pragma unroll
    for (int c = 0; c < 7; c++){
      int G = c*256 + tid;
      const uint16_t* src;
      if (G < 1536){
        int r = G >> 5, gp = G & 31;
        src = Whh + (size_t)((r>>4)*256 + cs*16 + (r&15))*DHID + (gp ^ (r&7))*8;
      } else {
        int G2 = G - 1536, r = G2 >> 3, gp = G2 & 7;
        src = Wih + (size_t)((r>>4)*256 + cs*16 + (r&15))*DHEAD + (gp ^ (r&7))*8;
      }
      __builtin_amdgcn_global_load_lds(
          (const __attribute__((address_space(1))) uint32_t*)src,
          (__attribute__((address_space(3))) uint32_t*)(Wb + (size_t)G*8),
          16, 0, 0);
    }
    if (tid < 128){
      int G = 1792 + tid;
      int G2 = G - 1536, r = G2 >> 3, gp = G2 & 7;
      const uint16_t* src = Wih + (size_t)((r>>4)*256 + cs*16 + (r&15))*DHEAD + (gp ^ (r&7))*8;
      __builtin_amdgcn_global_load_lds(
          (const __attribute__((address_space(1))) uint32_t*)src,
          (__attribute__((address_space(3))) uint32_t*)(Wb + (size_t)G*8),
          16, 0, 0);
    }
  };

  stage_async(0);

  // ---- phase A: info = ctx @ Wo^T (2 tiles) — overlaps DMA(0) ----
  f32x4 ai[2][4] = {};
  #pragma unroll
  for (int kk = 0; kk < 8; kk++){
    bf16x8 bw[4];
    #pragma unroll
    for (int j = 0; j < 4; j++)
      bw[j] = *(const bf16x8*)(Wo + (size_t)(j*16 + lr)*DHID + kk*32 + lg*8);
    #pragma unroll
    for (int t = 0; t < 2; t++){
      bf16x8 ac = *(const bf16x8*)(ctxp + (size_t)(r0 + wrow + t*16 + lr)*DHID + kk*32 + lg*8);
      #pragma unroll
      for (int j = 0; j < 4; j++) ai[t][j] = MFMA(ac, bw[j], ai[t][j]);
    }
  }
  #pragma unroll
  for (int t = 0; t < 2; t++)
  #pragma unroll
  for (int j = 0; j < 4; j++)
  #pragma unroll
  for (int rr = 0; rr < 4; rr++){
    int row = wrow + t*16 + lg*4 + rr, col = j*16 + lr;
    Is[row*64 + ((col>>3) ^ (row&7))*8 + (col&7)] = f2bf(ai[t][j][rr]);
  }

  bf16x8 aL[2][8];
  #pragma unroll
  for (int t = 0; t < 2; t++)
  #pragma unroll
  for (int kk = 0; kk < 8; kk++)
    aL[t][kk] = *(const bf16x8*)(lat + (size_t)(r0 + wrow + t*16 + lr)*DHID + kk*32 + lg*8);

  uint32_t u4[2];
  #pragma unroll
  for (int t = 0; t < 2; t++)
    u4[t] = *(const uint32_t*)(upd + r0 + wrow + t*16 + lg*4);

  __syncthreads();     // drains DMA(0); Is, bias ready

  const float LOG2E = 1.44269504f;
  for (int cs = 0; cs < 16; cs++){
    const uint16_t* WhhS = Wb;
    const uint16_t* WihS = Wb + 12288;

    f32x4 arz[2][2] = {};
    f32x4 gin[2] = {}, ghn[2] = {};

    #pragma unroll
    for (int kk = 0; kk < 2; kk++){
      int off = ((kk*4 + lg) ^ (lr & 7)) * 8;
      bf16x8 br = *(const bf16x8*)(WihS + (0*16 + lr)*64 + off);
      bf16x8 bz = *(const bf16x8*)(WihS + (1*16 + lr)*64 + off);
      bf16x8 bn = *(const bf16x8*)(WihS + (2*16 + lr)*64 + off);
      #pragma unroll
      for (int t = 0; t < 2; t++){
        bf16x8 a = *(const bf16x8*)(Is + (wrow + t*16 + lr)*64 + off);
        arz[0][t] = MFMA(a, br, arz[0][t]);
        arz[1][t] = MFMA(a, bz, arz[1][t]);
        gin[t]    = MFMA(a, bn, gin[t]);
      }
    }
    #pragma unroll
    for (int kk = 0; kk < 8; kk++){
      int off = ((kk*4 + lg) ^ (lr & 7)) * 8;
      bf16x8 br = *(const bf16x8*)(WhhS + (0*16 + lr)*256 + off);
      bf16x8 bz = *(const bf16x8*)(WhhS + (1*16 + lr)*256 + off);
      bf16x8 bn = *(const bf16x8*)(WhhS + (2*16 + lr)*256 + off);
      #pragma unroll
      for (int t = 0; t < 2; t++){
        arz[0][t] = MFMA(aL[t][kk], br, arz[0][t]);
        arz[1][t] = MFMA(aL[t][kk], bz, arz[1][t]);
        ghn[t]    = MFMA(aL[t][kk], bn, ghn[t]);
      }
    }

    __syncthreads();                 // barrier 1: all waves done reading Wb
    if (cs < 15) stage_async(cs+1);  // DMA lands during epilogue

    int col = cs*16 + lr;
    float brz0 = bf2f(biasS[col])     + bf2f(biasS[768+col]);
    float brz1 = bf2f(biasS[256+col]) + bf2f(biasS[1024+col]);
    float bin_ = bf2f(biasS[512+col]);
    float bhn  = bf2f(biasS[1280+col]);
    #pragma unroll
    for (int t = 0; t < 2; t++)
    #pragma unroll
    for (int rr = 0; rr < 4; rr++){
      int row = wrow + t*16 + lg*4 + rr;
      float hv = bf2f(lat[(size_t)(r0+row)*DHID + col]);
      float xr = arz[0][t][rr] + brz0;
      float xz = arz[1][t][rr] + brz1;
      float rg = __builtin_amdgcn_rcpf(1.f + __builtin_amdgcn_exp2f(-xr*LOG2E));
      float zg = __builtin_amdgcn_rcpf(1.f + __builtin_amdgcn_exp2f(-xz*LOG2E));
      float nx = (gin[t][rr] + bin_) + rg*(ghn[t][rr] + bhn);
      nx = fminf(10.f, fmaxf(-10.f, nx));
      float e2 = __builtin_amdgcn_exp2f(-2.f*LOG2E*nx);
      float ng = (1.f - e2) * __builtin_amdgcn_rcpf(1.f + e2);
      float hp = (1.f - zg)*ng + zg*hv;
      float ov = ((u4[t] >> (rr*8)) & 1u) ? hp : hv;
      lat_out[(size_t)(r0+row)*DHID + col] = f2bf(ov);
    }
    if (cs < 15) __syncthreads();    // barrier 2: drains DMA before next reads
  }
}

extern "C" void kernel_launch(void* const* d_in, const int* in_sizes, int n_in,
                              void* d_out, int out_size, void* d_ws, size_t ws_size,
                              hipStream_t stream)
{
  (void)in_sizes; (void)n_in; (void)out_size;
  const void* latent = d_in[0];
  const int*  mask   = (const int*)d_in[1];
  const void* Wq  = d_in[3]; const void* bq  = d_in[4];
  const void* Wk  = d_in[5]; const void* bk  = d_in[6];
  const void* Wv  = d_in[7]; const void* bv  = d_in[8];
  const void* Wo  = d_in[9];
  const void* Wih = d_in[10]; const void* Whh = d_in[11];
  const void* bih = d_in[12]; const void* bhh = d_in[13];

  uint8_t* p = (uint8_t*)d_ws;
  uint32_t* flag = (uint32_t*)p;            p += 256;
  uint16_t* Wqc  = (uint16_t*)p;            p += 65536*2;
  uint16_t* Wkc  = (uint16_t*)p;            p += 65536*2;
  uint16_t* Wvc  = (uint16_t*)p;            p += 65536*2;
  uint16_t* Woc  = (uint16_t*)p;            p += 16384*2;
  uint16_t* Wihc = (uint16_t*)p;            p += 49152*2;
  uint16_t* Whhc = (uint16_t*)p;            p += 196608*2;
  uint16_t* bqc  = (uint16_t*)p;            p += 512;
  uint16_t* bkc  = (uint16_t*)p;            p += 512;
  uint16_t* bvc  = (uint16_t*)p;            p += 512;
  uint16_t* bihc = (uint16_t*)p;            p += 1536;
  uint16_t* bhhc = (uint16_t*)p;            p += 1536;
  uint8_t* chunk0 = p;
  size_t reserved = (size_t)(chunk0 - (uint8_t*)d_ws);
  const size_t perb = 5ull*65536 + 2048 + 128;

  const int Btot = 1024;
  int CB = (int)((ws_size > reserved ? ws_size - reserved : 0) / perb);
  if (CB > Btot) CB = Btot;
  if (CB < 1)    CB = 1;

  auto cgrid = [](int n){ int b = (n/8 + 255)/256; if (b > 2048) b = 2048; if (b < 1) b = 1; return (unsigned)b; };

  k_detect<<<1, 64, 0, stream>>>((const uint32_t*)latent, flag);
  k_convw<<<225, 256, 0, stream>>>(flag, Wq, Wk, Wv, Wo, Wih, Whh,
                                   bq, bk, bv, bih, bhh, Wqc);

  for (int b0 = 0; b0 < Btot; b0 += CB){
    int cb = (Btot - b0 < CB) ? (Btot - b0) : CB;
    int rows = cb * 128;
    int nelem = rows * DHID;
    uint8_t* q = chunk0;
    uint16_t* L    = (uint16_t*)q; q += (size_t)cb*65536;
    uint16_t* q_ws = (uint16_t*)q; q += (size_t)cb*65536;
    uint16_t* k_ws = (uint16_t*)q; q += (size_t)cb*65536;
    uint16_t* v_ws = (uint16_t*)q; q += (size_t)cb*65536;
    uint16_t* c_ws = (uint16_t*)q; q += (size_t)cb*65536;
    unsigned long long* packed = (unsigned long long*)q; q += (size_t)cb*2048;
    unsigned char* updp = (unsigned char*)q;

    uint16_t* dout_b = (uint16_t*)d_out + (size_t)b0*NTOK*DHID;   // bf16 view

    k_conv<<<cgrid(nelem), 256, 0, stream>>>(latent, (unsigned long long)b0*NTOK*DHID, L, flag, nelem);
    k_maskpack<<<dim3(rows/4), 256, 0, stream>>>(mask + (size_t)b0*NTOK*NTOK, packed, updp, rows);

    for (int layer = 0; layer < 2; layer++){
      k_qkv <<<dim3(rows/64),  256, 65536, stream>>>(L, Wqc,bqc, Wkc,bkc, Wvc,bvc, q_ws, k_ws, v_ws);
      k_attn<<<dim3(cb*NHEAD), 256, 51200, stream>>>(q_ws, k_ws, v_ws, packed, c_ws);
      k_gru <<<dim3(rows/128), 256, 50176, stream>>>(c_ws, L, Woc, Wihc, Whhc, bihc, bhhc, updp,
                                                     L, dout_b, flag, layer);
    }
    k_store<<<cgrid(nelem), 256, 0, stream>>>(L, (void*)((float*)d_out + (size_t)b0*NTOK*DHID), 0, flag, nelem);
  }
}